// Round 1
// baseline (409.923 us; speedup 1.0000x reference)
//
#include <hip/hip_runtime.h>
#include <hip/hip_bf16.h>

#define DG 16384
#define NNZ 262144
#define BB 128

typedef __attribute__((ext_vector_type(8))) short bf16x8;
typedef __attribute__((ext_vector_type(4))) float f32x4;
typedef __attribute__((ext_vector_type(4))) unsigned short us4;

// ---- workspace layout (bytes) ----
#define WS_ROWPTR 0            // 16385 ints
#define WS_XIN16  66048        // 128*16384 bf16 = 4,194,304
#define WS_T      4260352      // 6 * 16384*128*4 = 50,331,648  (partials alias this after combine)
#define WS_XPOOL  54592000     // 128*65536 bf16 = 16,777,216
#define WS_XNN1   71369216     // 128*512*4
#define WS_DEC2   71631360     // 128*512 bf16
#define WS_XNN2   71762432     // 128*256*4
#define WS_N1     71893504     // 256*4
#define WS_TAIL   71894528     // 128*4

__device__ __forceinline__ unsigned short f2bf(float f) {
  __hip_bfloat16 h = __float2bfloat16(f);
  return __builtin_bit_cast(unsigned short, h);
}

// ---- prep: rowptr binary search + x_in -> bf16 ----
__global__ __launch_bounds__(256) void prep_kernel(
    const float* __restrict__ x_in, const int* __restrict__ rows,
    int* __restrict__ rowptr, unsigned short* __restrict__ xin16) {
  int idx = blockIdx.x * 256 + threadIdx.x;   // 524288 threads
  if (idx <= DG) {
    int lo = 0, hi = NNZ;
    while (lo < hi) { int mid = (lo + hi) >> 1; if (rows[mid] < idx) lo = mid + 1; else hi = mid; }
    rowptr[idx] = lo;
  }
  f32x4 v = ((const f32x4*)x_in)[idx];
  us4 o; o[0] = f2bf(v[0]); o[1] = f2bf(v[1]); o[2] = f2bf(v[2]); o[3] = f2bf(v[3]);
  ((us4*)xin16)[idx] = o;
}

// ---- transpose x_in [128,16384] -> T0 [16384,128] ----
__global__ __launch_bounds__(1024) void transpose_kernel(
    const float* __restrict__ x_in, float* __restrict__ T0) {
  __shared__ float t[32][33];
  int v0 = blockIdx.x * 32, b0 = blockIdx.y * 32;
  t[threadIdx.y][threadIdx.x] = x_in[(size_t)(b0 + threadIdx.y) * DG + v0 + threadIdx.x];
  __syncthreads();
  T0[(size_t)(v0 + threadIdx.y) * BB + b0 + threadIdx.x] = t[threadIdx.x][threadIdx.y];
}

// ---- CSR SpMM + Chebyshev update: out = scale*L@X - prev ----
__global__ __launch_bounds__(128) void spmm_cheby(
    const int* __restrict__ rowptr, const int* __restrict__ cols,
    const float* __restrict__ vals, const float* __restrict__ X,
    const float* __restrict__ Tprev, float* __restrict__ Tout, float scale) {
  int r = blockIdx.x, b = threadIdx.x;
  int e0 = rowptr[r], e1 = rowptr[r + 1];
  float acc = 0.f;
  int e = e0;
  for (; e + 4 <= e1; e += 4) {
    int c0 = cols[e], c1 = cols[e + 1], c2 = cols[e + 2], c3 = cols[e + 3];
    float v0 = vals[e], v1 = vals[e + 1], v2 = vals[e + 2], v3 = vals[e + 3];
    float x0 = X[c0 * BB + b], x1 = X[c1 * BB + b], x2 = X[c2 * BB + b], x3 = X[c3 * BB + b];
    acc += v0 * x0; acc += v1 * x1; acc += v2 * x2; acc += v3 * x3;
  }
  for (; e < e1; ++e) acc += vals[e] * X[cols[e] * BB + b];
  float out = scale * acc;
  if (Tprev) out -= Tprev[r * BB + b];
  Tout[r * BB + b] = out;
}

// ---- fused Cheby-combine + bias + ReLU + MaxPool(8) -> bf16 [128, 65536] ----
__global__ __launch_bounds__(256) void combine_pool(
    const float* __restrict__ Tbase, const float* __restrict__ W,
    const float* __restrict__ bias, unsigned short* __restrict__ xpool) {
  int vp = blockIdx.x;                  // 2048 pooled groups
  __shared__ float tile[6][8][128];
  __shared__ float Wl[192];
  __shared__ float bl[32];
  for (int i = threadIdx.x; i < 192; i += 256) Wl[i] = W[i];
  if (threadIdx.x < 32) bl[threadIdx.x] = bias[threadIdx.x];
  for (int i = threadIdx.x; i < 6144; i += 256) {
    int k = i >> 10, rem = i & 1023, j = rem >> 7, b = rem & 127;
    tile[k][j][b] = Tbase[(size_t)k * 2097152 + (size_t)(vp * 8 + j) * BB + b];
  }
  __syncthreads();
  for (int p = threadIdx.x; p < 4096; p += 256) {
    int b = p >> 5, f = p & 31;
    float m = -1e30f;
    #pragma unroll
    for (int j = 0; j < 8; ++j) {
      float s = bl[f];
      #pragma unroll
      for (int k = 0; k < 6; ++k) s += tile[k][j][b] * Wl[f * 6 + k];
      m = fmaxf(m, s);
    }
    m = fmaxf(m, 0.f);
    xpool[(size_t)b * 65536 + vp * 32 + f] = f2bf(m);
  }
}

// ---- MFMA GEMM: out[128,N] = A_bf16[128,K] @ W_f32[N,K]^T (direct or split-K partials) ----
__global__ __launch_bounds__(256) void gemm_mfma(
    const unsigned short* __restrict__ A, const float* __restrict__ W,
    float* __restrict__ outp, const float* __restrict__ bias,
    int K, int N, int Kchunk, int relu, int partial) {
  int wid = threadIdx.x >> 6, lane = threadIdx.x & 63;
  int lr = lane & 15, lg = lane >> 4;
  int n0 = blockIdx.x * 128 + wid * 32;
  int kbeg = blockIdx.y * Kchunk;
  f32x4 acc[8][2];
  #pragma unroll
  for (int mt = 0; mt < 8; ++mt) {
    acc[mt][0] = (f32x4){0.f, 0.f, 0.f, 0.f};
    acc[mt][1] = (f32x4){0.f, 0.f, 0.f, 0.f};
  }
  const unsigned short* Abase = A + lr * K + lg * 8;
  for (int kb = kbeg; kb < kbeg + Kchunk; kb += 32) {
    bf16x8 af[8];
    #pragma unroll
    for (int mt = 0; mt < 8; ++mt)
      af[mt] = *(const bf16x8*)(Abase + mt * 16 * K + kb);
    #pragma unroll
    for (int nt = 0; nt < 2; ++nt) {
      const float* wp = W + (size_t)(n0 + nt * 16 + lr) * K + kb + lg * 8;
      f32x4 w0 = *(const f32x4*)wp;
      f32x4 w1 = *(const f32x4*)(wp + 4);
      bf16x8 bfv;
      bfv[0] = (short)f2bf(w0[0]); bfv[1] = (short)f2bf(w0[1]);
      bfv[2] = (short)f2bf(w0[2]); bfv[3] = (short)f2bf(w0[3]);
      bfv[4] = (short)f2bf(w1[0]); bfv[5] = (short)f2bf(w1[1]);
      bfv[6] = (short)f2bf(w1[2]); bfv[7] = (short)f2bf(w1[3]);
      #pragma unroll
      for (int mt = 0; mt < 8; ++mt)
        acc[mt][nt] = __builtin_amdgcn_mfma_f32_16x16x32_bf16(af[mt], bfv, acc[mt][nt], 0, 0, 0);
    }
  }
  if (partial) {
    float* P = outp + (size_t)blockIdx.y * 128 * (size_t)N;
    #pragma unroll
    for (int mt = 0; mt < 8; ++mt)
      #pragma unroll
      for (int nt = 0; nt < 2; ++nt) {
        int col = n0 + nt * 16 + lr;
        #pragma unroll
        for (int r = 0; r < 4; ++r) {
          int row = mt * 16 + lg * 4 + r;
          P[(size_t)row * N + col] = acc[mt][nt][r];
        }
      }
  } else {
    #pragma unroll
    for (int mt = 0; mt < 8; ++mt)
      #pragma unroll
      for (int nt = 0; nt < 2; ++nt) {
        int col = n0 + nt * 16 + lr;
        #pragma unroll
        for (int r = 0; r < 4; ++r) {
          int row = mt * 16 + lg * 4 + r;
          float v = acc[mt][nt][r] + bias[col];
          if (relu) v = fmaxf(v, 0.f);
          outp[(size_t)row * N + col] = v;
        }
      }
  }
}

// ---- split-K reduce + bias + optional ReLU ----
__global__ __launch_bounds__(256) void reduce_kernel(
    const float* __restrict__ P, const float* __restrict__ bias,
    float* __restrict__ out, int S, int total, int N, int relu) {
  int idx = blockIdx.x * 256 + threadIdx.x;
  if (idx >= total) return;
  float s = 0.f;
  for (int i = 0; i < S; ++i) s += P[(size_t)i * total + idx];
  float v = s + bias[idx % N];
  if (relu) v = fmaxf(v, 0.f);
  out[idx] = v;
}

// ---- small fp32 GEMM (fc2 / nn2): grid = N, block = 128 (batch) ----
__global__ __launch_bounds__(128) void small_gemm(
    const float* __restrict__ A, const float* __restrict__ W,
    const float* __restrict__ bias, float* __restrict__ outf,
    unsigned short* __restrict__ outb, int K, int relu) {
  int o = blockIdx.x, b = threadIdx.x, N = gridDim.x;
  const f32x4* a4 = (const f32x4*)(A + (size_t)b * K);
  const f32x4* w4 = (const f32x4*)(W + (size_t)o * K);
  float acc = 0.f;
  for (int k = 0; k < K / 4; ++k) {
    f32x4 x = a4[k], y = w4[k];
    acc += x[0] * y[0] + x[1] * y[1] + x[2] * y[2] + x[3] * y[3];
  }
  float v = acc + bias[o];
  if (relu) v = fmaxf(v, 0.f);
  if (outf) outf[(size_t)b * N + o] = v;
  if (outb) outb[(size_t)b * N + o] = f2bf(v);
}

// ---- GCN4 meta-graph chain (batch-invariant): single block ----
__global__ __launch_bounds__(256) void g4_kernel(
    const float* __restrict__ xe_g, const float* __restrict__ Lmg_g,
    const float* __restrict__ W4, const float* __restrict__ b4,
    const float* __restrict__ Wg1, const float* __restrict__ bg1,
    const float* __restrict__ Wg2, const float* __restrict__ bg2,
    float* __restrict__ tail) {
  __shared__ float Lm[100], Tg[4][640], xc[320], xg96[96], h1[128];
  int t = threadIdx.x;
  for (int i = t; i < 640; i += 256) Tg[0][i] = xe_g[i];
  for (int i = t; i < 100; i += 256) Lm[i] = Lmg_g[i];
  __syncthreads();
  for (int i = t; i < 640; i += 256) {
    int v = i >> 6, f = i & 63; float s = 0.f;
    #pragma unroll
    for (int u = 0; u < 10; ++u) s += Lm[v * 10 + u] * Tg[0][u * 64 + f];
    Tg[1][i] = s;
  }
  __syncthreads();
  for (int kk = 2; kk < 4; ++kk) {
    for (int i = t; i < 640; i += 256) {
      int v = i >> 6, f = i & 63; float s = 0.f;
      #pragma unroll
      for (int u = 0; u < 10; ++u) s += Lm[v * 10 + u] * Tg[kk - 1][u * 64 + f];
      Tg[kk][i] = 2.f * s - Tg[kk - 2][i];
    }
    __syncthreads();
  }
  for (int i = t; i < 320; i += 256) {
    int v = i >> 5, fo = i & 31; float s = b4[fo];
    for (int fin = 0; fin < 64; ++fin)
      #pragma unroll
      for (int k = 0; k < 4; ++k) s += Tg[k][v * 64 + fin] * W4[fo * 256 + fin * 4 + k];
    xc[i] = fmaxf(s, 0.f);
  }
  __syncthreads();
  for (int i = t; i < 96; i += 256) {
    int g = i >> 5, fo = i & 31;
    xg96[i] = fmaxf(fmaxf(xc[(3 * g) * 32 + fo], xc[(3 * g + 1) * 32 + fo]),
                    xc[(3 * g + 2) * 32 + fo]);
  }
  __syncthreads();
  for (int o = t; o < 128; o += 256) {
    float s = bg1[o];
    for (int i2 = 0; i2 < 96; ++i2) s += xg96[i2] * Wg1[o * 96 + i2];
    h1[o] = fmaxf(s, 0.f);
  }
  __syncthreads();
  for (int o = t; o < 64; o += 256) {
    float s = bg2[o];
    for (int i2 = 0; i2 < 128; ++i2) s += h1[i2] * Wg2[o * 128 + i2];
    tail[o] = fmaxf(s, 0.f);
  }
}

// ---- wave-per-output dot + bias + ReLU (nn14 / nn24) ----
__global__ __launch_bounds__(64) void dot_relu_kernel(
    const float* __restrict__ x, const float* __restrict__ W,
    const float* __restrict__ bias, float* __restrict__ out, int K) {
  int o = blockIdx.x, lane = threadIdx.x;
  float a = 0.f;
  for (int i = lane; i < K; i += 64) a += x[i] * W[(size_t)o * K + i];
  #pragma unroll
  for (int s = 32; s > 0; s >>= 1) a += __shfl_down(a, s);
  if (lane == 0) out[o] = fmaxf(a + bias[o], 0.f);
}

// ---- fcsum + log_softmax: one block per batch row ----
__global__ __launch_bounds__(64) void fcsum_kernel(
    const float* __restrict__ hidden, const float* __restrict__ xnn2,
    const float* __restrict__ tail, const float* __restrict__ Ws,
    const float* __restrict__ bs, float* __restrict__ logp) {
  int b = blockIdx.x, lane = threadIdx.x;
  __shared__ float emb[896];
  for (int i = lane; i < 896; i += 64)
    emb[i] = (i < 512) ? hidden[b * 512 + i]
           : (i < 768) ? xnn2[b * 256 + (i - 512)]
                       : tail[i - 768];
  __syncthreads();
  float l[10];
  #pragma unroll
  for (int o = 0; o < 10; ++o) {
    float a = 0.f;
    for (int i = lane; i < 896; i += 64) a += emb[i] * Ws[o * 896 + i];
    #pragma unroll
    for (int s = 32; s > 0; s >>= 1) a += __shfl_down(a, s);
    l[o] = __shfl(a, 0) + bs[o];
  }
  float m = l[0];
  #pragma unroll
  for (int o = 1; o < 10; ++o) m = fmaxf(m, l[o]);
  float sum = 0.f;
  #pragma unroll
  for (int o = 0; o < 10; ++o) sum += expf(l[o] - m);
  float lse = m + logf(sum);
  #pragma unroll
  for (int o = 0; o < 10; ++o)
    if (lane == o) logp[b * 10 + o] = l[o] - lse;
}

extern "C" void kernel_launch(void* const* d_in, const int* in_sizes, int n_in,
                              void* d_out, int out_size, void* d_ws, size_t ws_size,
                              hipStream_t stream) {
  const float* x_in    = (const float*)d_in[0];
  const float* x_embed = (const float*)d_in[1];
  const int*   L_rows  = (const int*)d_in[3];
  const int*   L_cols  = (const int*)d_in[4];
  const float* L_vals  = (const float*)d_in[5];
  const float* L_mg    = (const float*)d_in[6];
  const float* cl1_W = (const float*)d_in[7],  *cl1_b = (const float*)d_in[8];
  const float* fc1_W = (const float*)d_in[9],  *fc1_b = (const float*)d_in[10];
  const float* fc2_W = (const float*)d_in[11], *fc2_b = (const float*)d_in[12];
  const float* fc3_W = (const float*)d_in[13], *fc3_b = (const float*)d_in[14];
  const float* nn1_W = (const float*)d_in[15], *nn1_b = (const float*)d_in[16];
  const float* nn2_W = (const float*)d_in[17], *nn2_b = (const float*)d_in[18];
  const float* cl4_W = (const float*)d_in[19], *cl4_b = (const float*)d_in[20];
  const float* fcg1_W = (const float*)d_in[21], *fcg1_b = (const float*)d_in[22];
  const float* fcg2_W = (const float*)d_in[23], *fcg2_b = (const float*)d_in[24];
  const float* nn14_W = (const float*)d_in[25], *nn14_b = (const float*)d_in[26];
  const float* nn24_W = (const float*)d_in[27], *nn24_b = (const float*)d_in[28];
  const float* fcsum_W = (const float*)d_in[29], *fcsum_b = (const float*)d_in[30];

  char* ws = (char*)d_ws;
  int* rowptr = (int*)(ws + WS_ROWPTR);
  unsigned short* xin16 = (unsigned short*)(ws + WS_XIN16);
  float* T = (float*)(ws + WS_T);              // 6 planes of 2097152 floats
  unsigned short* xpool = (unsigned short*)(ws + WS_XPOOL);
  float* part = (float*)(ws + WS_T);           // aliases T (dead after combine)
  float* xnn1 = (float*)(ws + WS_XNN1);
  unsigned short* dec2 = (unsigned short*)(ws + WS_DEC2);
  float* xnn2 = (float*)(ws + WS_XNN2);
  float* n1 = (float*)(ws + WS_N1);
  float* tail = (float*)(ws + WS_TAIL);

  float* out0 = (float*)d_out;                 // x_decode_gae [128,16384]
  float* hidden = out0 + 2097152;              // x_hidden_gae [128,512]
  float* logp = out0 + 2097152 + 65536;        // [128,10]

  // tails first (independent of the big chain)
  g4_kernel<<<1, 256, 0, stream>>>(x_embed, L_mg, cl4_W, cl4_b, fcg1_W, fcg1_b,
                                   fcg2_W, fcg2_b, tail);
  dot_relu_kernel<<<256, 64, 0, stream>>>(x_embed, nn14_W, nn14_b, n1, 640);
  dot_relu_kernel<<<64, 64, 0, stream>>>(n1, nn24_W, nn24_b, tail + 64, 256);

  prep_kernel<<<2048, 256, 0, stream>>>(x_in, L_rows, rowptr, xin16);
  transpose_kernel<<<dim3(512, 4), dim3(32, 32), 0, stream>>>(x_in, T);

  // Chebyshev recursion T1..T5
  spmm_cheby<<<DG, 128, 0, stream>>>(rowptr, L_cols, L_vals, T,               nullptr,       T + 1 * 2097152, 1.f);
  spmm_cheby<<<DG, 128, 0, stream>>>(rowptr, L_cols, L_vals, T + 1 * 2097152, T,             T + 2 * 2097152, 2.f);
  spmm_cheby<<<DG, 128, 0, stream>>>(rowptr, L_cols, L_vals, T + 2 * 2097152, T + 1 * 2097152, T + 3 * 2097152, 2.f);
  spmm_cheby<<<DG, 128, 0, stream>>>(rowptr, L_cols, L_vals, T + 3 * 2097152, T + 2 * 2097152, T + 4 * 2097152, 2.f);
  spmm_cheby<<<DG, 128, 0, stream>>>(rowptr, L_cols, L_vals, T + 4 * 2097152, T + 3 * 2097152, T + 5 * 2097152, 2.f);

  combine_pool<<<2048, 256, 0, stream>>>(T, cl1_W, cl1_b, xpool);

  // nn1: [128,16384] @ [512,16384]^T  (split-K 64, uses part which aliases T -> run AFTER combine)
  gemm_mfma<<<dim3(4, 64), 256, 0, stream>>>(xin16, nn1_W, part, nullptr, 16384, 512, 256, 0, 1);
  reduce_kernel<<<256, 256, 0, stream>>>(part, nn1_b, xnn1, 64, 65536, 512, 1);
  small_gemm<<<256, 128, 0, stream>>>(xnn1, nn2_W, nn2_b, xnn2, nullptr, 512, 1);

  // fc1: [128,65536] @ [512,65536]^T  (split-K 64)
  gemm_mfma<<<dim3(4, 64), 256, 0, stream>>>(xpool, fc1_W, part, nullptr, 65536, 512, 1024, 0, 1);
  reduce_kernel<<<256, 256, 0, stream>>>(part, fc1_b, hidden, 64, 65536, 512, 1);

  // fc2 -> bf16 activations for fc3
  small_gemm<<<512, 128, 0, stream>>>(hidden, fc2_W, fc2_b, nullptr, dec2, 512, 1);
  // fc3: [128,512] @ [16384,512]^T -> x_decode_gae (direct, bias, no relu)
  gemm_mfma<<<dim3(128, 1), 256, 0, stream>>>(dec2, fc3_W, out0, fc3_b, 512, 16384, 512, 0, 0);

  // final head
  fcsum_kernel<<<128, 64, 0, stream>>>(hidden, xnn2, tail, fcsum_W, fcsum_b, logp);
}

// Round 2
// 383.420 us; speedup vs baseline: 1.0691x; 1.0691x over previous
//
#include <hip/hip_runtime.h>
#include <hip/hip_bf16.h>

#define DG 16384
#define NNZ 262144
#define BB 128

typedef __attribute__((ext_vector_type(8))) short bf16x8;
typedef __attribute__((ext_vector_type(4))) float f32x4;
typedef __attribute__((ext_vector_type(4))) unsigned short us4;

// ---- workspace layout (bytes) ----
#define WS_ROWPTR 0            // 16385 ints
#define WS_XIN16  66048        // 128*16384 bf16 = 4,194,304
#define WS_T      4260352      // 6 * 16384*128*4 = 50,331,648  (partials alias this after combine)
#define WS_XPOOL  54592000     // 128*65536 bf16 = 16,777,216
#define WS_XNN1   71369216     // 128*512*4
#define WS_DEC2   71631360     // 128*512 bf16
#define WS_XNN2   71762432     // 128*256*4
#define WS_N1     71893504     // 256*4
#define WS_TAIL   71894528     // 128*4

__device__ __forceinline__ unsigned short f2bf(float f) {
  __hip_bfloat16 h = __float2bfloat16(f);
  return __builtin_bit_cast(unsigned short, h);
}

// ---- prep: rowptr binary search + x_in -> bf16 ----
__global__ __launch_bounds__(256) void prep_kernel(
    const float* __restrict__ x_in, const int* __restrict__ rows,
    int* __restrict__ rowptr, unsigned short* __restrict__ xin16) {
  int idx = blockIdx.x * 256 + threadIdx.x;   // 524288 threads
  if (idx <= DG) {
    int lo = 0, hi = NNZ;
    while (lo < hi) { int mid = (lo + hi) >> 1; if (rows[mid] < idx) lo = mid + 1; else hi = mid; }
    rowptr[idx] = lo;
  }
  f32x4 v = ((const f32x4*)x_in)[idx];
  us4 o; o[0] = f2bf(v[0]); o[1] = f2bf(v[1]); o[2] = f2bf(v[2]); o[3] = f2bf(v[3]);
  ((us4*)xin16)[idx] = o;
}

// ---- transpose x_in [128,16384] -> T0 [16384,128] ----
__global__ __launch_bounds__(1024) void transpose_kernel(
    const float* __restrict__ x_in, float* __restrict__ T0) {
  __shared__ float t[32][33];
  int v0 = blockIdx.x * 32, b0 = blockIdx.y * 32;
  t[threadIdx.y][threadIdx.x] = x_in[(size_t)(b0 + threadIdx.y) * DG + v0 + threadIdx.x];
  __syncthreads();
  T0[(size_t)(v0 + threadIdx.y) * BB + b0 + threadIdx.x] = t[threadIdx.x][threadIdx.y];
}

// ---- CSR SpMM + Chebyshev update: out = scale*L@X - prev ----
__global__ __launch_bounds__(128) void spmm_cheby(
    const int* __restrict__ rowptr, const int* __restrict__ cols,
    const float* __restrict__ vals, const float* __restrict__ X,
    const float* __restrict__ Tprev, float* __restrict__ Tout, float scale) {
  int r = blockIdx.x, b = threadIdx.x;
  int e0 = rowptr[r], e1 = rowptr[r + 1];
  float acc0 = 0.f, acc1 = 0.f;
  int e = e0;
  for (; e + 8 <= e1; e += 8) {
    int c0 = cols[e], c1 = cols[e + 1], c2 = cols[e + 2], c3 = cols[e + 3];
    int c4 = cols[e + 4], c5 = cols[e + 5], c6 = cols[e + 6], c7 = cols[e + 7];
    float v0 = vals[e], v1 = vals[e + 1], v2 = vals[e + 2], v3 = vals[e + 3];
    float v4 = vals[e + 4], v5 = vals[e + 5], v6 = vals[e + 6], v7 = vals[e + 7];
    float x0 = X[c0 * BB + b], x1 = X[c1 * BB + b], x2 = X[c2 * BB + b], x3 = X[c3 * BB + b];
    float x4 = X[c4 * BB + b], x5 = X[c5 * BB + b], x6 = X[c6 * BB + b], x7 = X[c7 * BB + b];
    acc0 += v0 * x0; acc1 += v1 * x1; acc0 += v2 * x2; acc1 += v3 * x3;
    acc0 += v4 * x4; acc1 += v5 * x5; acc0 += v6 * x6; acc1 += v7 * x7;
  }
  for (; e < e1; ++e) acc0 += vals[e] * X[cols[e] * BB + b];
  float out = scale * (acc0 + acc1);
  if (Tprev) out -= Tprev[r * BB + b];
  Tout[r * BB + b] = out;
}

// ---- fused Cheby-combine + bias + ReLU + MaxPool(8) -> bf16 [128, 65536] ----
__global__ __launch_bounds__(256) void combine_pool(
    const float* __restrict__ Tbase, const float* __restrict__ W,
    const float* __restrict__ bias, unsigned short* __restrict__ xpool) {
  int vp = blockIdx.x;                  // 2048 pooled groups
  __shared__ float tile[6][8][128];
  __shared__ float Wl[192];
  __shared__ float bl[32];
  for (int i = threadIdx.x; i < 192; i += 256) Wl[i] = W[i];
  if (threadIdx.x < 32) bl[threadIdx.x] = bias[threadIdx.x];
  for (int i = threadIdx.x; i < 6144; i += 256) {
    int k = i >> 10, rem = i & 1023, j = rem >> 7, b = rem & 127;
    tile[k][j][b] = Tbase[(size_t)k * 2097152 + (size_t)(vp * 8 + j) * BB + b];
  }
  __syncthreads();
  for (int p = threadIdx.x; p < 4096; p += 256) {
    int b = p >> 5, f = p & 31;
    float m = -1e30f;
    #pragma unroll
    for (int j = 0; j < 8; ++j) {
      float s = bl[f];
      #pragma unroll
      for (int k = 0; k < 6; ++k) s += tile[k][j][b] * Wl[f * 6 + k];
      m = fmaxf(m, s);
    }
    m = fmaxf(m, 0.f);
    xpool[(size_t)b * 65536 + vp * 32 + f] = f2bf(m);
  }
}

__device__ __forceinline__ f32x4 ntload4(const float* p) {
  return __builtin_nontemporal_load((const f32x4*)p);
}

// ---- MFMA GEMM v2: block = 32 output cols, 4 waves split K, LDS reduce ----
// out[128,N] = A_bf16[128,K] @ W_f32[N,K]^T  (partial plane per blockIdx.y, or final)
__global__ __launch_bounds__(256) void gemm_mfma2(
    const unsigned short* __restrict__ A, const float* __restrict__ W,
    float* __restrict__ outp, const float* __restrict__ bias,
    int K, int N, int Kchunk, int relu, int partial) {
  int wid = threadIdx.x >> 6, lane = threadIdx.x & 63;
  int lr = lane & 15, lg = lane >> 4;
  int n0 = blockIdx.x * 32;
  int klen = Kchunk >> 2;
  int kbeg = blockIdx.y * Kchunk + wid * klen;
  f32x4 acc[8][2];
  #pragma unroll
  for (int mt = 0; mt < 8; ++mt) {
    acc[mt][0] = (f32x4){0.f, 0.f, 0.f, 0.f};
    acc[mt][1] = (f32x4){0.f, 0.f, 0.f, 0.f};
  }
  const unsigned short* Abase = A + lr * K + lg * 8;
  const float* W0 = W + (size_t)(n0 + lr) * K + lg * 8;
  const float* W1 = W + (size_t)(n0 + 16 + lr) * K + lg * 8;
  for (int kb = kbeg; kb < kbeg + klen; kb += 32) {
    bf16x8 af[8];
    #pragma unroll
    for (int mt = 0; mt < 8; ++mt)
      af[mt] = *(const bf16x8*)(Abase + mt * 16 * K + kb);
    f32x4 wa0 = ntload4(W0 + kb), wa1 = ntload4(W0 + kb + 4);
    f32x4 wb0 = ntload4(W1 + kb), wb1 = ntload4(W1 + kb + 4);
    bf16x8 b0, b1;
    b0[0] = (short)f2bf(wa0[0]); b0[1] = (short)f2bf(wa0[1]);
    b0[2] = (short)f2bf(wa0[2]); b0[3] = (short)f2bf(wa0[3]);
    b0[4] = (short)f2bf(wa1[0]); b0[5] = (short)f2bf(wa1[1]);
    b0[6] = (short)f2bf(wa1[2]); b0[7] = (short)f2bf(wa1[3]);
    b1[0] = (short)f2bf(wb0[0]); b1[1] = (short)f2bf(wb0[1]);
    b1[2] = (short)f2bf(wb0[2]); b1[3] = (short)f2bf(wb0[3]);
    b1[4] = (short)f2bf(wb1[0]); b1[5] = (short)f2bf(wb1[1]);
    b1[6] = (short)f2bf(wb1[2]); b1[7] = (short)f2bf(wb1[3]);
    #pragma unroll
    for (int mt = 0; mt < 8; ++mt) {
      acc[mt][0] = __builtin_amdgcn_mfma_f32_16x16x32_bf16(af[mt], b0, acc[mt][0], 0, 0, 0);
      acc[mt][1] = __builtin_amdgcn_mfma_f32_16x16x32_bf16(af[mt], b1, acc[mt][1], 0, 0, 0);
    }
  }
  // cross-wave reduction: waves 2,3 -> LDS; 0,1 add; 1 -> LDS; 0 adds + writes
  __shared__ float red[2][4096];
  float* accf = (float*)acc;   // 64 floats, flat j = mt*8 + nt*4 + r
  if (wid >= 2) {
    #pragma unroll
    for (int j = 0; j < 64; ++j) red[wid - 2][j * 64 + lane] = accf[j];
  }
  __syncthreads();
  if (wid < 2) {
    #pragma unroll
    for (int j = 0; j < 64; ++j) accf[j] += red[wid][j * 64 + lane];
  }
  __syncthreads();
  if (wid == 1) {
    #pragma unroll
    for (int j = 0; j < 64; ++j) red[0][j * 64 + lane] = accf[j];
  }
  __syncthreads();
  if (wid == 0) {
    #pragma unroll
    for (int j = 0; j < 64; ++j) accf[j] += red[0][j * 64 + lane];
    if (partial) {
      float* P = outp + (size_t)blockIdx.y * 128 * (size_t)N;
      #pragma unroll
      for (int mt = 0; mt < 8; ++mt)
        #pragma unroll
        for (int nt = 0; nt < 2; ++nt) {
          int col = n0 + nt * 16 + lr;
          #pragma unroll
          for (int r = 0; r < 4; ++r) {
            int row = mt * 16 + lg * 4 + r;
            P[(size_t)row * N + col] = accf[mt * 8 + nt * 4 + r];
          }
        }
    } else {
      #pragma unroll
      for (int mt = 0; mt < 8; ++mt)
        #pragma unroll
        for (int nt = 0; nt < 2; ++nt) {
          int col = n0 + nt * 16 + lr;
          float bcol = bias[col];
          #pragma unroll
          for (int r = 0; r < 4; ++r) {
            int row = mt * 16 + lg * 4 + r;
            float v = accf[mt * 8 + nt * 4 + r] + bcol;
            if (relu) v = fmaxf(v, 0.f);
            outp[(size_t)row * N + col] = v;
          }
        }
    }
  }
}

// ---- split-K reduce + bias + optional ReLU ----
__global__ __launch_bounds__(256) void reduce_kernel(
    const float* __restrict__ P, const float* __restrict__ bias,
    float* __restrict__ out, int S, int total, int N, int relu) {
  int idx = blockIdx.x * 256 + threadIdx.x;
  if (idx >= total) return;
  float s = 0.f;
  for (int i = 0; i < S; ++i) s += P[(size_t)i * total + idx];
  float v = s + bias[idx % N];
  if (relu) v = fmaxf(v, 0.f);
  out[idx] = v;
}

// ---- small fp32 GEMM (fc2 / nn2): grid = N, block = 128 (batch) ----
__global__ __launch_bounds__(128) void small_gemm(
    const float* __restrict__ A, const float* __restrict__ W,
    const float* __restrict__ bias, float* __restrict__ outf,
    unsigned short* __restrict__ outb, int K, int relu) {
  int o = blockIdx.x, b = threadIdx.x, N = gridDim.x;
  const f32x4* a4 = (const f32x4*)(A + (size_t)b * K);
  const f32x4* w4 = (const f32x4*)(W + (size_t)o * K);
  float acc = 0.f;
  for (int k = 0; k < K / 4; ++k) {
    f32x4 x = a4[k], y = w4[k];
    acc += x[0] * y[0] + x[1] * y[1] + x[2] * y[2] + x[3] * y[3];
  }
  float v = acc + bias[o];
  if (relu) v = fmaxf(v, 0.f);
  if (outf) outf[(size_t)b * N + o] = v;
  if (outb) outb[(size_t)b * N + o] = f2bf(v);
}

// ---- GCN4 meta-graph chain (batch-invariant): single block ----
__global__ __launch_bounds__(256) void g4_kernel(
    const float* __restrict__ xe_g, const float* __restrict__ Lmg_g,
    const float* __restrict__ W4, const float* __restrict__ b4,
    const float* __restrict__ Wg1, const float* __restrict__ bg1,
    const float* __restrict__ Wg2, const float* __restrict__ bg2,
    float* __restrict__ tail) {
  __shared__ float Lm[100], Tg[4][640], xc[320], xg96[96], h1[128];
  int t = threadIdx.x;
  for (int i = t; i < 640; i += 256) Tg[0][i] = xe_g[i];
  for (int i = t; i < 100; i += 256) Lm[i] = Lmg_g[i];
  __syncthreads();
  for (int i = t; i < 640; i += 256) {
    int v = i >> 6, f = i & 63; float s = 0.f;
    #pragma unroll
    for (int u = 0; u < 10; ++u) s += Lm[v * 10 + u] * Tg[0][u * 64 + f];
    Tg[1][i] = s;
  }
  __syncthreads();
  for (int kk = 2; kk < 4; ++kk) {
    for (int i = t; i < 640; i += 256) {
      int v = i >> 6, f = i & 63; float s = 0.f;
      #pragma unroll
      for (int u = 0; u < 10; ++u) s += Lm[v * 10 + u] * Tg[kk - 1][u * 64 + f];
      Tg[kk][i] = 2.f * s - Tg[kk - 2][i];
    }
    __syncthreads();
  }
  for (int i = t; i < 320; i += 256) {
    int v = i >> 5, fo = i & 31; float s = b4[fo];
    for (int fin = 0; fin < 64; ++fin)
      #pragma unroll
      for (int k = 0; k < 4; ++k) s += Tg[k][v * 64 + fin] * W4[fo * 256 + fin * 4 + k];
    xc[i] = fmaxf(s, 0.f);
  }
  __syncthreads();
  for (int i = t; i < 96; i += 256) {
    int g = i >> 5, fo = i & 31;
    xg96[i] = fmaxf(fmaxf(xc[(3 * g) * 32 + fo], xc[(3 * g + 1) * 32 + fo]),
                    xc[(3 * g + 2) * 32 + fo]);
  }
  __syncthreads();
  for (int o = t; o < 128; o += 256) {
    float s = bg1[o];
    for (int i2 = 0; i2 < 96; ++i2) s += xg96[i2] * Wg1[o * 96 + i2];
    h1[o] = fmaxf(s, 0.f);
  }
  __syncthreads();
  for (int o = t; o < 64; o += 256) {
    float s = bg2[o];
    for (int i2 = 0; i2 < 128; ++i2) s += h1[i2] * Wg2[o * 128 + i2];
    tail[o] = fmaxf(s, 0.f);
  }
}

// ---- wave-per-output dot + bias + ReLU (nn14 / nn24) ----
__global__ __launch_bounds__(64) void dot_relu_kernel(
    const float* __restrict__ x, const float* __restrict__ W,
    const float* __restrict__ bias, float* __restrict__ out, int K) {
  int o = blockIdx.x, lane = threadIdx.x;
  float a = 0.f;
  for (int i = lane; i < K; i += 64) a += x[i] * W[(size_t)o * K + i];
  #pragma unroll
  for (int s = 32; s > 0; s >>= 1) a += __shfl_down(a, s);
  if (lane == 0) out[o] = fmaxf(a + bias[o], 0.f);
}

// ---- fcsum + log_softmax: one block per batch row ----
__global__ __launch_bounds__(64) void fcsum_kernel(
    const float* __restrict__ hidden, const float* __restrict__ xnn2,
    const float* __restrict__ tail, const float* __restrict__ Ws,
    const float* __restrict__ bs, float* __restrict__ logp) {
  int b = blockIdx.x, lane = threadIdx.x;
  __shared__ float emb[896];
  for (int i = lane; i < 896; i += 64)
    emb[i] = (i < 512) ? hidden[b * 512 + i]
           : (i < 768) ? xnn2[b * 256 + (i - 512)]
                       : tail[i - 768];
  __syncthreads();
  float l[10];
  #pragma unroll
  for (int o = 0; o < 10; ++o) {
    float a = 0.f;
    for (int i = lane; i < 896; i += 64) a += emb[i] * Ws[o * 896 + i];
    #pragma unroll
    for (int s = 32; s > 0; s >>= 1) a += __shfl_down(a, s);
    l[o] = __shfl(a, 0) + bs[o];
  }
  float m = l[0];
  #pragma unroll
  for (int o = 1; o < 10; ++o) m = fmaxf(m, l[o]);
  float sum = 0.f;
  #pragma unroll
  for (int o = 0; o < 10; ++o) sum += expf(l[o] - m);
  float lse = m + logf(sum);
  #pragma unroll
  for (int o = 0; o < 10; ++o)
    if (lane == o) logp[b * 10 + o] = l[o] - lse;
}

extern "C" void kernel_launch(void* const* d_in, const int* in_sizes, int n_in,
                              void* d_out, int out_size, void* d_ws, size_t ws_size,
                              hipStream_t stream) {
  const float* x_in    = (const float*)d_in[0];
  const float* x_embed = (const float*)d_in[1];
  const int*   L_rows  = (const int*)d_in[3];
  const int*   L_cols  = (const int*)d_in[4];
  const float* L_vals  = (const float*)d_in[5];
  const float* L_mg    = (const float*)d_in[6];
  const float* cl1_W = (const float*)d_in[7],  *cl1_b = (const float*)d_in[8];
  const float* fc1_W = (const float*)d_in[9],  *fc1_b = (const float*)d_in[10];
  const float* fc2_W = (const float*)d_in[11], *fc2_b = (const float*)d_in[12];
  const float* fc3_W = (const float*)d_in[13], *fc3_b = (const float*)d_in[14];
  const float* nn1_W = (const float*)d_in[15], *nn1_b = (const float*)d_in[16];
  const float* nn2_W = (const float*)d_in[17], *nn2_b = (const float*)d_in[18];
  const float* cl4_W = (const float*)d_in[19], *cl4_b = (const float*)d_in[20];
  const float* fcg1_W = (const float*)d_in[21], *fcg1_b = (const float*)d_in[22];
  const float* fcg2_W = (const float*)d_in[23], *fcg2_b = (const float*)d_in[24];
  const float* nn14_W = (const float*)d_in[25], *nn14_b = (const float*)d_in[26];
  const float* nn24_W = (const float*)d_in[27], *nn24_b = (const float*)d_in[28];
  const float* fcsum_W = (const float*)d_in[29], *fcsum_b = (const float*)d_in[30];

  char* ws = (char*)d_ws;
  int* rowptr = (int*)(ws + WS_ROWPTR);
  unsigned short* xin16 = (unsigned short*)(ws + WS_XIN16);
  float* T = (float*)(ws + WS_T);              // 6 planes of 2097152 floats
  unsigned short* xpool = (unsigned short*)(ws + WS_XPOOL);
  float* part = (float*)(ws + WS_T);           // aliases T (dead after combine)
  float* xnn1 = (float*)(ws + WS_XNN1);
  unsigned short* dec2 = (unsigned short*)(ws + WS_DEC2);
  float* xnn2 = (float*)(ws + WS_XNN2);
  float* n1 = (float*)(ws + WS_N1);
  float* tail = (float*)(ws + WS_TAIL);

  float* out0 = (float*)d_out;                 // x_decode_gae [128,16384]
  float* hidden = out0 + 2097152;              // x_hidden_gae [128,512]
  float* logp = out0 + 2097152 + 65536;        // [128,10]

  // tails first (independent of the big chain)
  g4_kernel<<<1, 256, 0, stream>>>(x_embed, L_mg, cl4_W, cl4_b, fcg1_W, fcg1_b,
                                   fcg2_W, fcg2_b, tail);
  dot_relu_kernel<<<256, 64, 0, stream>>>(x_embed, nn14_W, nn14_b, n1, 640);
  dot_relu_kernel<<<64, 64, 0, stream>>>(n1, nn24_W, nn24_b, tail + 64, 256);

  prep_kernel<<<2048, 256, 0, stream>>>(x_in, L_rows, rowptr, xin16);
  transpose_kernel<<<dim3(512, 4), dim3(32, 32), 0, stream>>>(x_in, T);

  // Chebyshev recursion T1..T5
  spmm_cheby<<<DG, 128, 0, stream>>>(rowptr, L_cols, L_vals, T,               nullptr,       T + 1 * 2097152, 1.f);
  spmm_cheby<<<DG, 128, 0, stream>>>(rowptr, L_cols, L_vals, T + 1 * 2097152, T,             T + 2 * 2097152, 2.f);
  spmm_cheby<<<DG, 128, 0, stream>>>(rowptr, L_cols, L_vals, T + 2 * 2097152, T + 1 * 2097152, T + 3 * 2097152, 2.f);
  spmm_cheby<<<DG, 128, 0, stream>>>(rowptr, L_cols, L_vals, T + 3 * 2097152, T + 2 * 2097152, T + 4 * 2097152, 2.f);
  spmm_cheby<<<DG, 128, 0, stream>>>(rowptr, L_cols, L_vals, T + 4 * 2097152, T + 3 * 2097152, T + 5 * 2097152, 2.f);

  combine_pool<<<2048, 256, 0, stream>>>(T, cl1_W, cl1_b, xpool);

  // nn1: [128,16384] @ [512,16384]^T  (split-K 32 planes; part aliases T -> after combine)
  gemm_mfma2<<<dim3(16, 32), 256, 0, stream>>>(xin16, nn1_W, part, nullptr, 16384, 512, 512, 0, 1);
  reduce_kernel<<<256, 256, 0, stream>>>(part, nn1_b, xnn1, 32, 65536, 512, 1);
  small_gemm<<<256, 128, 0, stream>>>(xnn1, nn2_W, nn2_b, xnn2, nullptr, 512, 1);

  // fc1: [128,65536] @ [512,65536]^T  (split-K 64 planes)
  gemm_mfma2<<<dim3(16, 64), 256, 0, stream>>>(xpool, fc1_W, part, nullptr, 65536, 512, 1024, 0, 1);
  reduce_kernel<<<256, 256, 0, stream>>>(part, fc1_b, hidden, 64, 65536, 512, 1);

  // fc2 -> bf16 activations for fc3
  small_gemm<<<512, 128, 0, stream>>>(hidden, fc2_W, fc2_b, nullptr, dec2, 512, 1);
  // fc3: [128,512] @ [16384,512]^T -> x_decode_gae (direct, bias, no relu)
  gemm_mfma2<<<dim3(512, 1), 256, 0, stream>>>(dec2, fc3_W, out0, fc3_b, 512, 16384, 512, 0, 0);

  // final head
  fcsum_kernel<<<128, 64, 0, stream>>>(hidden, xnn2, tail, fcsum_W, fcsum_b, logp);
}